// Round 5
// baseline (527.289 us; speedup 1.0000x reference)
//
#include <hip/hip_runtime.h>

#define L_DIM 16384
#define C_DIM 256
#define NV 8
#define NH 4
#define DH 64
#define TL 4          // l's per block (32 token rows)
#define NTHREADS 256  // 4 waves

// LDS strides (in elements)
#define QKP 132       // f16 per row for q|k
#define VVP 68        // f16 per row for v
#define GPAD 68       // fp32 per row for g1s (16B-aligned rows)
// A/ctx/att: 32 rows x 256 f16, 16B slots XOR-swizzled: slot' = slot ^ row

typedef __attribute__((ext_vector_type(8))) _Float16 f16x8;
typedef __attribute__((ext_vector_type(4))) _Float16 f16x4;
typedef __attribute__((ext_vector_type(2))) _Float16 f16x2;
typedef __attribute__((ext_vector_type(4))) float f32x4;

union F8u { f16x8 v; f16x2 p[4]; };

// ---------------- prep: view_info + pack fp16 weights into MFMA fragment order
// Packed layout: frag index ((chunk*4 + nt)*8 + kc)*64 + lane, 8 f16 each.
// Element j = W[chunkrow + nt*16 + (lane&15)][(lane>>4)*8 + kc*32 + j].
__global__ void prep_kernel(const float* __restrict__ vw, const float* __restrict__ vb,
                            const float* __restrict__ w_in, const float* __restrict__ w_out,
                            const float* __restrict__ w_g1,
                            float* __restrict__ view_info, _Float16* __restrict__ win_pk,
                            _Float16* __restrict__ wout_pk, _Float16* __restrict__ wg1_pk){
  int tid = threadIdx.x, bid = blockIdx.x;
  if (bid == 0){
    int c = tid;                       // 256 threads, one channel each
    const float4* vr = (const float4*)(vw + c*C_DIM);
    float rs = 0.f;
#pragma unroll 8
    for (int k = 0; k < 64; k++){ float4 x = vr[k]; rs += x.x + x.y + x.z + x.w; }
    float b = vb[c];
    for (int n = 0; n < NV; n++) view_info[n*C_DIM + c] = (n * 0.125f) * rs + b;
  }
  int gid = bid * blockDim.x + tid;
  int stride = gridDim.x * blockDim.x;
  const int NWIN = 24576, NWOUT = 8192, NWG = 2048;
  for (int f = gid; f < NWIN + NWOUT + NWG; f += stride){
    if (f < NWIN){
      int lane = f & 63, kc = (f>>6)&7, nt = (f>>9)&3, pc = f>>11;   // pc = h*3+p
      int p = pc % 3, h = pc / 3;
      int row = p*C_DIM + h*DH + nt*16 + (lane&15);
      int col = (lane>>4)*8 + kc*32;
      const float* src = w_in + (long)row*C_DIM + col;
      _Float16* d = win_pk + (long)f*8;
#pragma unroll
      for (int j = 0; j < 8; j++) d[j] = (_Float16)src[j];
    } else if (f < NWIN + NWOUT){
      int f2 = f - NWIN;
      int lane = f2 & 63, kc = (f2>>6)&7, nt = (f2>>9)&3, cc = f2>>11;
      int row = cc*64 + nt*16 + (lane&15);
      int col = (lane>>4)*8 + kc*32;
      const float* src = w_out + (long)row*C_DIM + col;
      _Float16* d = wout_pk + (long)f2*8;
#pragma unroll
      for (int j = 0; j < 8; j++) d[j] = (_Float16)src[j];
    } else {
      int f3 = f - NWIN - NWOUT;
      int lane = f3 & 63, kc = (f3>>6)&7, nt = (f3>>9)&3;
      int row = nt*16 + (lane&15);
      int col = (lane>>4)*8 + kc*32;
      const float* src = w_g1 + (long)row*C_DIM + col;
      _Float16* d = wg1_pk + (long)f3*8;
#pragma unroll
      for (int j = 0; j < 8; j++) d[j] = (_Float16)src[j];
    }
  }
}

// ---------------- fused main kernel: one block = 4 l's (32 tokens), 4 waves ----
// Register-diet build: __launch_bounds__(256,5) caps total regs at 102 so 5
// waves/SIMD can be resident (20 waves/CU). Peak concurrent accumulator+ring
// demand halved by splitting qkv (q,k | v passes) and out-proj (nt halves).
// LDS carve (32768 B -> 5 blocks/CU):
//   region1 [0,16384):  A [32][256]h swz -> ctx overlay -> { g1s [32][68]f (8704B)
//                        + misc at 8704: gl[32],wgt[32],red1[128],red2[128],mus[4],rvs[4] }
//   region2 [16384,32768): qk [32][132]h + vv [32][68]h at +8448 -> att [32][256]h overlay
__global__ __launch_bounds__(NTHREADS, 5)
void fused_kernel(const float* __restrict__ feat,
                  const float* __restrict__ view_info,
                  const _Float16* __restrict__ win,
                  const _Float16* __restrict__ wout,
                  const _Float16* __restrict__ wg1,
                  const float* __restrict__ b_in,
                  const float* __restrict__ b_out,
                  const float* __restrict__ b_g1,
                  const float* __restrict__ w2,
                  const float* __restrict__ b2,
                  const float* __restrict__ ln_g,
                  const float* __restrict__ ln_b,
                  float* __restrict__ out)
{
  extern __shared__ char smem[];
  _Float16* A   = (_Float16*)smem;             // [32][256] swz
  _Float16* ctx = (_Float16*)smem;             // overlay after A dead
  float*    g1s = (float*)smem;                // overlay after ctx dead
  float* gl   = (float*)(smem + 8704);         // [32]
  float* wgt  = gl + 32;                       // [32]
  float* red1 = wgt + 32;                      // [128]
  float* red2 = red1 + 128;                    // [128]
  float* mus  = red2 + 128;                    // [4]
  float* rvs  = mus + 4;                       // [4]
  _Float16* qk  = (_Float16*)(smem + 16384);   // [32][132]
  _Float16* vv  = (_Float16*)(smem + 24832);   // [32][68]
  _Float16* att = (_Float16*)(smem + 16384);   // overlay after qk/vv dead

  const int tid  = threadIdx.x;
  const int wv   = tid >> 6, lane = tid & 63;
  const int quad = lane >> 4, l15 = lane & 15;

  const _Float16* wbin  = win  + (long)(wv*8)*512 + lane*8;   // + ((h*3+p)*32+kc)*512
  const _Float16* wbout = wout + (long)(wv*32)*512 + lane*8;  // + (nt*8+kc)*512
  const _Float16* wbg1  = wg1  + (long)(wv*8)*512 + lane*8;   // + kc*512

#define WQK(dst, h_, kc_) do { \
  dst[0] = *(const f16x8*)(wbin + (((h_)*3+0)*32 + (kc_))*512); \
  dst[1] = *(const f16x8*)(wbin + (((h_)*3+1)*32 + (kc_))*512); } while(0)
#define WVLD(h_, kc_) (*(const f16x8*)(wbin + (((h_)*3+2)*32 + (kc_))*512))
#define WOUT2(dst, ntb, kc_) do { \
  dst[0] = *(const f16x8*)(wbout + (((ntb)+0)*8 + (kc_))*512); \
  dst[1] = *(const f16x8*)(wbout + (((ntb)+1)*8 + (kc_))*512); } while(0)

  // ---- stage A = f16(features + view_info) into LDS, cooperative (once) ----
  {
    int row = tid >> 3, j = tid & 7;            // 32 rows x 8 threads
    int n = row & 7, lloc = row >> 3;
    long l = (long)blockIdx.x * TL + lloc;
    const float* fb = feat + ((long)n * L_DIM + l) * C_DIM + j*32;
    const float* vb = view_info + n * C_DIM + j*32;
    _Float16* arow = A + row*256;
#pragma unroll
    for (int i = 0; i < 4; i++){
      float4 x0 = *(const float4*)(fb + i*8);
      float4 x1 = *(const float4*)(fb + i*8 + 4);
      float4 v0 = *(const float4*)(vb + i*8);
      float4 v1 = *(const float4*)(vb + i*8 + 4);
      f16x8 hf;
      hf[0] = (_Float16)(x0.x+v0.x); hf[1] = (_Float16)(x0.y+v0.y);
      hf[2] = (_Float16)(x0.z+v0.z); hf[3] = (_Float16)(x0.w+v0.w);
      hf[4] = (_Float16)(x1.x+v1.x); hf[5] = (_Float16)(x1.y+v1.y);
      hf[6] = (_Float16)(x1.z+v1.z); hf[7] = (_Float16)(x1.w+v1.w);
      int s = j*4 + i;
      *(f16x8*)(arow + ((s ^ row))*8) = hf;
    }
  }
  __syncthreads();

  f16x8 cpk0, cpk1, cpk2;   // per-head ctx stash (written to LDS at h=3)

#pragma unroll
  for (int h = 0; h < NH; h++){
    if (h) __syncthreads();                 // prior attention done reading qk/vv
    // ---- pass A: q,k (p=0,1); acc 16 regs + ring 16 regs ----
    {
      f32x4 z = {0.f,0.f,0.f,0.f};
      f32x4 acc00=z, acc01=z, acc10=z, acc11=z;
      f16x8 wa[2][2];
      WQK(wa[0], h, 0);
      WQK(wa[1], h, 1);
#pragma unroll
      for (int kc = 0; kc < 8; kc++){
        int s0 = quad + 4*kc;
        int r1 = 16 + l15;
        f16x8 a0 = *(const f16x8*)(A + l15*256 + ((s0 ^ l15))*8);
        f16x8 a1 = *(const f16x8*)(A + r1*256  + ((s0 ^ r1))*8);
        acc00 = __builtin_amdgcn_mfma_f32_16x16x32_f16(wa[kc&1][0], a0, acc00, 0,0,0);
        acc01 = __builtin_amdgcn_mfma_f32_16x16x32_f16(wa[kc&1][0], a1, acc01, 0,0,0);
        acc10 = __builtin_amdgcn_mfma_f32_16x16x32_f16(wa[kc&1][1], a0, acc10, 0,0,0);
        acc11 = __builtin_amdgcn_mfma_f32_16x16x32_f16(wa[kc&1][1], a1, acc11, 0,0,0);
        if (kc < 6) WQK(wa[kc&1], h, kc+2);
      }
      int c4 = wv*16 + quad*4;               // 4 consecutive output cols (in chunk)
#pragma unroll
      for (int p = 0; p < 2; p++){
        float4 b4 = *(const float4*)(b_in + p*C_DIM + h*DH + c4);
        float bb[4] = {b4.x, b4.y, b4.z, b4.w};
        f16x4 s0v, s1v;
#pragma unroll
        for (int r = 0; r < 4; r++){
          s0v[r] = (_Float16)((p ? acc10[r] : acc00[r]) + bb[r]);
          s1v[r] = (_Float16)((p ? acc11[r] : acc01[r]) + bb[r]);
        }
        *(f16x4*)(qk + l15*QKP      + p*64 + c4) = s0v;
        *(f16x4*)(qk + (16+l15)*QKP + p*64 + c4) = s1v;
      }
    }
    // ---- pass B: v (p=2); acc 8 regs + ring 8 regs ----
    {
      f32x4 z = {0.f,0.f,0.f,0.f};
      f32x4 acc20=z, acc21=z;
      f16x8 wb0 = WVLD(h, 0);
      f16x8 wb1 = WVLD(h, 1);
#pragma unroll
      for (int kc = 0; kc < 8; kc++){
        int s0 = quad + 4*kc;
        int r1 = 16 + l15;
        f16x8 a0 = *(const f16x8*)(A + l15*256 + ((s0 ^ l15))*8);
        f16x8 a1 = *(const f16x8*)(A + r1*256  + ((s0 ^ r1))*8);
        f16x8 w = (kc & 1) ? wb1 : wb0;
        acc20 = __builtin_amdgcn_mfma_f32_16x16x32_f16(w, a0, acc20, 0,0,0);
        acc21 = __builtin_amdgcn_mfma_f32_16x16x32_f16(w, a1, acc21, 0,0,0);
        if (kc < 6){ if (kc & 1) wb1 = WVLD(h, kc+2); else wb0 = WVLD(h, kc+2); }
      }
      int c4 = wv*16 + quad*4;
      float4 b4 = *(const float4*)(b_in + 2*C_DIM + h*DH + c4);
      float bb[4] = {b4.x, b4.y, b4.z, b4.w};
      f16x4 s0v, s1v;
#pragma unroll
      for (int r = 0; r < 4; r++){
        s0v[r] = (_Float16)(acc20[r] + bb[r]);
        s1v[r] = (_Float16)(acc21[r] + bb[r]);
      }
      *(f16x4*)(vv + l15*VVP      + c4) = s0v;
      *(f16x4*)(vv + (16+l15)*VVP + c4) = s1v;
    }
    __syncthreads();                        // q,k,v complete for this head
    // ---- attention for head h: wave wv handles l_loc = wv, lane = nn*8+mm ----
    {
      int nn = lane >> 3, mm = lane & 7;
      int tq = wv*8 + nn;
      const _Float16* qrow = qk + tq*QKP;              // broadcast over mm
      const _Float16* krow = qk + (wv*8 + mm)*QKP + 64;
      float s = 0.f;
#pragma unroll
      for (int d8 = 0; d8 < 8; d8++){
        F8u q8, k8;
        q8.v = *(const f16x8*)(qrow + d8*8);
        k8.v = *(const f16x8*)(krow + d8*8);
#if __has_builtin(__builtin_amdgcn_fdot2)
#pragma unroll
        for (int j2 = 0; j2 < 4; j2++)
          s = __builtin_amdgcn_fdot2(q8.p[j2], k8.p[j2], s, false);
#else
#pragma unroll
        for (int j = 0; j < 8; j++) s += (float)q8.v[j] * (float)k8.v[j];
#endif
      }
      s *= 0.125f;                          // 1/sqrt(64)
      float mx = s;
#pragma unroll
      for (int o = 1; o < 8; o <<= 1) mx = fmaxf(mx, __shfl_xor(mx, o));
      float e = __expf(s - mx);
      float sum = e;
#pragma unroll
      for (int o = 1; o < 8; o <<= 1) sum += __shfl_xor(sum, o);
      float attnw = e / sum;
      // ctx: this thread owns d-slice [mm*8, mm*8+8) of token tq
      float c8[8] = {0,0,0,0,0,0,0,0};
#pragma unroll
      for (int mp = 0; mp < 8; mp++){
        float aw = __shfl(attnw, (nn<<3) | mp);
        f16x8 v8 = *(const f16x8*)(vv + (wv*8 + mp)*VVP + mm*8);
#pragma unroll
        for (int j = 0; j < 8; j++) c8[j] += aw * (float)v8[j];
      }
      f16x8 cp;
#pragma unroll
      for (int j = 0; j < 8; j++) cp[j] = (_Float16)c8[j];
      if (h == 0)      cpk0 = cp;
      else if (h == 1) cpk1 = cp;
      else if (h == 2) cpk2 = cp;
      else {
        // A is dead (last GEMM read barrier-separated): write all 4 heads' ctx
        _Float16* crow = ctx + tq*256;
        *(f16x8*)(crow + ((( 0 + mm) ^ tq))*8) = cpk0;
        *(f16x8*)(crow + ((( 8 + mm) ^ tq))*8) = cpk1;
        *(f16x8*)(crow + (((16 + mm) ^ tq))*8) = cpk2;
        *(f16x8*)(crow + (((24 + mm) ^ tq))*8) = cp;
      }
    }
  }
  __syncthreads();  // ctx complete; qk/vv dead -> att may be written

  // ================= attended = ctx @ W_out^T + b_out (fp16 MFMA) =============
  // two nt-halves: acc 16 regs + ring 16 regs each; ctx [0,16384) and att
  // [16384,32768) are disjoint, so stores need no extra barrier.
#pragma unroll
  for (int half = 0; half < 2; half++){
    int ntb = half*2;
    f32x4 z = {0.f,0.f,0.f,0.f};
    f32x4 acc0[2] = {z, z}, acc1[2] = {z, z};
    f16x8 wo[2][2];
    WOUT2(wo[0], ntb, 0);
    WOUT2(wo[1], ntb, 1);
#pragma unroll
    for (int kc = 0; kc < 8; kc++){
      int s0 = quad + 4*kc;
      int r1 = 16 + l15;
      f16x8 a0 = *(const f16x8*)(ctx + l15*256 + ((s0 ^ l15))*8);
      f16x8 a1 = *(const f16x8*)(ctx + r1*256  + ((s0 ^ r1))*8);
#pragma unroll
      for (int i = 0; i < 2; i++){
        acc0[i] = __builtin_amdgcn_mfma_f32_16x16x32_f16(wo[kc&1][i], a0, acc0[i], 0,0,0);
        acc1[i] = __builtin_amdgcn_mfma_f32_16x16x32_f16(wo[kc&1][i], a1, acc1[i], 0,0,0);
      }
      if (kc < 6) WOUT2(wo[kc&1], ntb, kc+2);
    }
#pragma unroll
    for (int i = 0; i < 2; i++){
      int c4 = wv*64 + (ntb+i)*16 + quad*4;
      float4 b4 = *(const float4*)(b_out + c4);
      float bb[4] = {b4.x, b4.y, b4.z, b4.w};
      f16x4 s0v, s1v;
#pragma unroll
      for (int r = 0; r < 4; r++){
        s0v[r] = (_Float16)(acc0[i][r] + bb[r]);
        s1v[r] = (_Float16)(acc1[i][r] + bb[r]);
      }
      int slot = c4 >> 3, jo = c4 & 7;
      *(f16x4*)(att + l15*256      + ((slot ^ l15))*8      + jo) = s0v;
      *(f16x4*)(att + (16+l15)*256 + ((slot ^ (16+l15)))*8 + jo) = s1v;
    }
  }
  __syncthreads();  // att ready; ctx dead -> g1s may be written

  // ================= gate hidden: g1 = relu(att @ Wg1^T + b) =================
  {
    f32x4 acc0 = {0.f,0.f,0.f,0.f}, acc1 = {0.f,0.f,0.f,0.f};
    f16x8 wg0 = *(const f16x8*)(wbg1);
    f16x8 wg1f = *(const f16x8*)(wbg1 + 512);
#pragma unroll
    for (int kc = 0; kc < 8; kc++){
      int s0 = quad + 4*kc;
      int r1 = 16 + l15;
      f16x8 a0 = *(const f16x8*)(att + l15*256 + ((s0 ^ l15))*8);
      f16x8 a1 = *(const f16x8*)(att + r1*256  + ((s0 ^ r1))*8);
      f16x8 w = (kc & 1) ? wg1f : wg0;
      acc0 = __builtin_amdgcn_mfma_f32_16x16x32_f16(w, a0, acc0, 0,0,0);
      acc1 = __builtin_amdgcn_mfma_f32_16x16x32_f16(w, a1, acc1, 0,0,0);
      if (kc < 6){
        if (kc & 1) wg1f = *(const f16x8*)(wbg1 + (kc+2)*512);
        else        wg0  = *(const f16x8*)(wbg1 + (kc+2)*512);
      }
    }
    int c4 = wv*16 + quad*4;                // 4 consecutive hidden cols
    float4 b4 = *(const float4*)(b_g1 + c4);
    float bb[4] = {b4.x, b4.y, b4.z, b4.w};
    float4 o0, o1;
    o0.x = fmaxf(acc0[0]+bb[0], 0.f); o0.y = fmaxf(acc0[1]+bb[1], 0.f);
    o0.z = fmaxf(acc0[2]+bb[2], 0.f); o0.w = fmaxf(acc0[3]+bb[3], 0.f);
    o1.x = fmaxf(acc1[0]+bb[0], 0.f); o1.y = fmaxf(acc1[1]+bb[1], 0.f);
    o1.z = fmaxf(acc1[2]+bb[2], 0.f); o1.w = fmaxf(acc1[3]+bb[3], 0.f);
    *(float4*)(g1s + l15*GPAD      + c4) = o0;
    *(float4*)(g1s + (16+l15)*GPAD + c4) = o1;
  }
  __syncthreads();

  // ---- gate scalar + sigmoid (8 threads per token, 32 tokens) ----
  {
    int t = tid >> 3, part = tid & 7;
    const float* g1r = g1s + t*GPAD + part*8;
    const float* w2p = w2 + part*8;
    float s = 0.f;
#pragma unroll
    for (int j = 0; j < 8; j++) s += g1r[j] * w2p[j];
    s += __shfl_xor(s, 1);
    s += __shfl_xor(s, 2);
    s += __shfl_xor(s, 4);
    if (part == 0) gl[t] = 1.f / (1.f + __expf(-(s + b2[0])));
  }
  __syncthreads();
  // ---- softmax over views (4 l's) ----
  if (tid < 4){
    float v[8]; float mx = -1e30f;
    for (int n = 0; n < 8; n++){ v[n] = gl[tid*8+n]; mx = fmaxf(mx, v[n]); }
    float sum = 0.f;
    for (int n = 0; n < 8; n++){ v[n] = __expf(v[n]-mx); sum += v[n]; }
    float inv = 1.f/sum;
    for (int n = 0; n < 8; n++) wgt[tid*8+n] = v[n]*inv;
  }
  __syncthreads();

  // ---- fused = sum_n w_n * attended, then LayerNorm over C ----
  float f8[8];
  const int lfl = tid >> 5, ccf = tid & 31;   // lfl 0..3 valid (tid<128)
  if (tid < 128){
    float wloc[8];
#pragma unroll
    for (int n = 0; n < 8; n++) wloc[n] = wgt[lfl*8+n];
#pragma unroll
    for (int j = 0; j < 8; j++) f8[j] = 0.f;
#pragma unroll
    for (int n = 0; n < 8; n++){
      int row = lfl*8 + n;
      f16x8 a8 = *(const f16x8*)(att + row*256 + ((ccf ^ row))*8);
      float aw = wloc[n];
#pragma unroll
      for (int j = 0; j < 8; j++) f8[j] += aw * (float)a8[j];
    }
    float s = 0.f, s2 = 0.f;
#pragma unroll
    for (int j = 0; j < 8; j++){ s += f8[j]; s2 += f8[j]*f8[j]; }
    red1[lfl*32 + ccf] = s;
    red2[lfl*32 + ccf] = s2;
  }
  __syncthreads();
  if (tid < 4){
    float s = 0.f, s2 = 0.f;
    for (int i = 0; i < 32; i++){ s += red1[tid*32+i]; s2 += red2[tid*32+i]; }
    float mu = s * (1.f/256.f);
    float var = s2 * (1.f/256.f) - mu*mu;
    mus[tid] = mu;
    rvs[tid] = rsqrtf(var + 1e-5f);
  }
  __syncthreads();
  if (tid < 128){
    float mu = mus[lfl], rv = rvs[lfl];
    long lg = (long)blockIdx.x * TL + lfl;
    float* op = out + lg * C_DIM + ccf*8;
    float o8[8];
#pragma unroll
    for (int j = 0; j < 8; j++){
      int c = ccf*8 + j;
      o8[j] = (f8[j]-mu)*rv*ln_g[c] + ln_b[c];
    }
    *(float4*)(op)   = make_float4(o8[0],o8[1],o8[2],o8[3]);
    *(float4*)(op+4) = make_float4(o8[4],o8[5],o8[6],o8[7]);
  }
}

extern "C" void kernel_launch(void* const* d_in, const int* in_sizes, int n_in,
                              void* d_out, int out_size, void* d_ws, size_t ws_size,
                              hipStream_t stream){
  const float* feat  = (const float*)d_in[0];
  const float* vw    = (const float*)d_in[1];
  const float* vb    = (const float*)d_in[2];
  const float* w_in  = (const float*)d_in[3];
  const float* b_in  = (const float*)d_in[4];
  const float* w_out = (const float*)d_in[5];
  const float* b_out = (const float*)d_in[6];
  const float* w_g1  = (const float*)d_in[7];
  const float* b_g1  = (const float*)d_in[8];
  const float* w2    = (const float*)d_in[9];
  const float* b2    = (const float*)d_in[10];
  const float* lng   = (const float*)d_in[11];
  const float* lnb   = (const float*)d_in[12];

  char* ws = (char*)d_ws;
  float*    view_info = (float*)ws;               //   8192 B
  _Float16* win_pk  = (_Float16*)(ws + 8192);     // 393216 B (packed fp16)
  _Float16* wout_pk = (_Float16*)(ws + 401408);   // 131072 B
  _Float16* wg1_pk  = (_Float16*)(ws + 532480);   //  32768 B   total 565248 B

  prep_kernel<<<256, 256, 0, stream>>>(vw, vb, w_in, w_out, w_g1,
                                       view_info, win_pk, wout_pk, wg1_pk);
  fused_kernel<<<L_DIM/TL, NTHREADS, 32768, stream>>>(
      feat, view_info, win_pk, wout_pk, wg1_pk,
      b_in, b_out, b_g1, w2, b2, lng, lnb, (float*)d_out);
}

// Round 7
// 428.485 us; speedup vs baseline: 1.2306x; 1.2306x over previous
//
#include <hip/hip_runtime.h>

#define L_DIM 16384
#define C_DIM 256
#define NV 8
#define NH 4
#define DH 64
#define TL 4          // l's per block (32 token rows)
#define NTHREADS 256  // 4 waves

// LDS strides (in elements)
#define QKP 132       // f16 per row for q|k
#define VVP 68        // f16 per row for v
#define GPAD 68       // fp32 per row for g1s (16B-aligned rows)
// A/ctx/att: 32 rows x 256 f16, 16B slots XOR-swizzled: slot' = slot ^ row

typedef __attribute__((ext_vector_type(8))) _Float16 f16x8;
typedef __attribute__((ext_vector_type(4))) _Float16 f16x4;
typedef __attribute__((ext_vector_type(2))) _Float16 f16x2;
typedef __attribute__((ext_vector_type(4))) float f32x4;

union F8u { f16x8 v; f16x2 p[4]; };

// ---------------- prep: view_info + pack fp16 weights into MFMA fragment order
// Packed layout: frag index ((chunk*4 + nt)*8 + kc)*64 + lane, 8 f16 each.
// Element j = W[chunkrow + nt*16 + (lane&15)][(lane>>4)*8 + kc*32 + j].
__global__ void prep_kernel(const float* __restrict__ vw, const float* __restrict__ vb,
                            const float* __restrict__ w_in, const float* __restrict__ w_out,
                            const float* __restrict__ w_g1,
                            float* __restrict__ view_info, _Float16* __restrict__ win_pk,
                            _Float16* __restrict__ wout_pk, _Float16* __restrict__ wg1_pk){
  int tid = threadIdx.x, bid = blockIdx.x;
  if (bid == 0){
    int c = tid;                       // 256 threads, one channel each
    const float4* vr = (const float4*)(vw + c*C_DIM);
    float rs = 0.f;
#pragma unroll 8
    for (int k = 0; k < 64; k++){ float4 x = vr[k]; rs += x.x + x.y + x.z + x.w; }
    float b = vb[c];
    for (int n = 0; n < NV; n++) view_info[n*C_DIM + c] = (n * 0.125f) * rs + b;
  }
  int gid = bid * blockDim.x + tid;
  int stride = gridDim.x * blockDim.x;
  const int NWIN = 24576, NWOUT = 8192, NWG = 2048;
  for (int f = gid; f < NWIN + NWOUT + NWG; f += stride){
    if (f < NWIN){
      int lane = f & 63, kc = (f>>6)&7, nt = (f>>9)&3, pc = f>>11;   // pc = h*3+p
      int p = pc % 3, h = pc / 3;
      int row = p*C_DIM + h*DH + nt*16 + (lane&15);
      int col = (lane>>4)*8 + kc*32;
      const float* src = w_in + (long)row*C_DIM + col;
      _Float16* d = win_pk + (long)f*8;
#pragma unroll
      for (int j = 0; j < 8; j++) d[j] = (_Float16)src[j];
    } else if (f < NWIN + NWOUT){
      int f2 = f - NWIN;
      int lane = f2 & 63, kc = (f2>>6)&7, nt = (f2>>9)&3, cc = f2>>11;
      int row = cc*64 + nt*16 + (lane&15);
      int col = (lane>>4)*8 + kc*32;
      const float* src = w_out + (long)row*C_DIM + col;
      _Float16* d = wout_pk + (long)f2*8;
#pragma unroll
      for (int j = 0; j < 8; j++) d[j] = (_Float16)src[j];
    } else {
      int f3 = f - NWIN - NWOUT;
      int lane = f3 & 63, kc = (f3>>6)&7, nt = (f3>>9)&3;
      int row = nt*16 + (lane&15);
      int col = (lane>>4)*8 + kc*32;
      const float* src = w_g1 + (long)row*C_DIM + col;
      _Float16* d = wg1_pk + (long)f3*8;
#pragma unroll
      for (int j = 0; j < 8; j++) d[j] = (_Float16)src[j];
    }
  }
}

// ---------------- fused main kernel: one block = 4 l's (32 tokens), 4 waves ----
// Consolidated best: swapped-operand MFMA (W as A-operand -> packed f16x4 stores),
// 2-deep weight rings that live strictly WITHIN one barrier phase (no cross-barrier
// register stashes except the 24-reg cpk ctx stash). __launch_bounds__(256,4):
// total regs/thread capped at 128 (arch+acc unified file) -- the natural point.
// LDS carve (32768 B):
//   region1 [0,16384):  A [32][256]h swz -> ctx overlay -> { g1s [32][68]f (8704B)
//                        + misc at 8704: gl[32],wgt[32],red1[128],red2[128],mus[4],rvs[4] }
//   region2 [16384,32768): qk [32][132]h + vv [32][68]h at +8448 -> att [32][256]h overlay
__global__ __launch_bounds__(NTHREADS, 4)
void fused_kernel(const float* __restrict__ feat,
                  const float* __restrict__ view_info,
                  const _Float16* __restrict__ win,
                  const _Float16* __restrict__ wout,
                  const _Float16* __restrict__ wg1,
                  const float* __restrict__ b_in,
                  const float* __restrict__ b_out,
                  const float* __restrict__ b_g1,
                  const float* __restrict__ w2,
                  const float* __restrict__ b2,
                  const float* __restrict__ ln_g,
                  const float* __restrict__ ln_b,
                  float* __restrict__ out)
{
  extern __shared__ char smem[];
  _Float16* A   = (_Float16*)smem;             // [32][256] swz
  _Float16* ctx = (_Float16*)smem;             // overlay after A dead
  float*    g1s = (float*)smem;                // overlay after ctx dead
  float* gl   = (float*)(smem + 8704);         // [32]
  float* wgt  = gl + 32;                       // [32]
  float* red1 = wgt + 32;                      // [128]
  float* red2 = red1 + 128;                    // [128]
  float* mus  = red2 + 128;                    // [4]
  float* rvs  = mus + 4;                       // [4]
  _Float16* qk  = (_Float16*)(smem + 16384);   // [32][132]
  _Float16* vv  = (_Float16*)(smem + 24832);   // [32][68]
  _Float16* att = (_Float16*)(smem + 16384);   // overlay after qk/vv dead

  const int tid  = threadIdx.x;
  const int wv   = tid >> 6, lane = tid & 63;
  const int quad = lane >> 4, l15 = lane & 15;

  const _Float16* wbin  = win  + (long)(wv*8)*512 + lane*8;   // + ((h*3+p)*32+kc)*512
  const _Float16* wbout = wout + (long)(wv*32)*512 + lane*8;  // + (nt*8+kc)*512
  const _Float16* wbg1  = wg1  + (long)(wv*8)*512 + lane*8;   // + kc*512

#define QSET(dst, h_, kc_) do { \
  dst[0] = *(const f16x8*)(wbin + (((h_)*3+0)*32 + (kc_))*512); \
  dst[1] = *(const f16x8*)(wbin + (((h_)*3+1)*32 + (kc_))*512); \
  dst[2] = *(const f16x8*)(wbin + (((h_)*3+2)*32 + (kc_))*512); } while(0)
#define OSET(dst, kc_) do { \
  dst[0] = *(const f16x8*)(wbout + (0*8+(kc_))*512); \
  dst[1] = *(const f16x8*)(wbout + (1*8+(kc_))*512); \
  dst[2] = *(const f16x8*)(wbout + (2*8+(kc_))*512); \
  dst[3] = *(const f16x8*)(wbout + (3*8+(kc_))*512); } while(0)

  // ---- stage A = f16(features + view_info) into LDS, cooperative (once) ----
  {
    int row = tid >> 3, j = tid & 7;            // 32 rows x 8 threads
    int n = row & 7, lloc = row >> 3;
    long l = (long)blockIdx.x * TL + lloc;
    const float* fb = feat + ((long)n * L_DIM + l) * C_DIM + j*32;
    const float* vb = view_info + n * C_DIM + j*32;
    _Float16* arow = A + row*256;
#pragma unroll
    for (int i = 0; i < 4; i++){
      float4 x0 = *(const float4*)(fb + i*8);
      float4 x1 = *(const float4*)(fb + i*8 + 4);
      float4 v0 = *(const float4*)(vb + i*8);
      float4 v1 = *(const float4*)(vb + i*8 + 4);
      f16x8 hf;
      hf[0] = (_Float16)(x0.x+v0.x); hf[1] = (_Float16)(x0.y+v0.y);
      hf[2] = (_Float16)(x0.z+v0.z); hf[3] = (_Float16)(x0.w+v0.w);
      hf[4] = (_Float16)(x1.x+v1.x); hf[5] = (_Float16)(x1.y+v1.y);
      hf[6] = (_Float16)(x1.z+v1.z); hf[7] = (_Float16)(x1.w+v1.w);
      int s = j*4 + i;
      *(f16x8*)(arow + ((s ^ row))*8) = hf;
    }
  }
  __syncthreads();

  f16x8 cpk0, cpk1, cpk2;   // per-head ctx stash (written to LDS at h=3)

#pragma unroll
  for (int h = 0; h < NH; h++){
    if (h) __syncthreads();                 // prior attention done reading qk/vv
    // ---- qkv GEMM for head h; weight ring lives entirely inside this phase ----
    {
      f16x8 wz[2][3];
      QSET(wz[0], h, 0);
      QSET(wz[1], h, 1);
      f32x4 z = {0.f,0.f,0.f,0.f};
      f32x4 acc[3][2];
#pragma unroll
      for (int p = 0; p < 3; p++){ acc[p][0] = z; acc[p][1] = z; }
#pragma unroll
      for (int kc = 0; kc < 8; kc++){
        int s0 = quad + 4*kc;
        int r1 = 16 + l15;
        f16x8 a0 = *(const f16x8*)(A + l15*256 + ((s0 ^ l15))*8);
        f16x8 a1 = *(const f16x8*)(A + r1*256  + ((s0 ^ r1))*8);
#pragma unroll
        for (int p = 0; p < 3; p++){
          acc[p][0] = __builtin_amdgcn_mfma_f32_16x16x32_f16(wz[kc&1][p], a0, acc[p][0], 0,0,0);
          acc[p][1] = __builtin_amdgcn_mfma_f32_16x16x32_f16(wz[kc&1][p], a1, acc[p][1], 0,0,0);
        }
        if (kc < 6) QSET(wz[kc&1], h, kc+2);   // in-phase 2-ahead ring
      }
      int c4 = wv*16 + quad*4;                 // 4 consecutive output cols (in chunk)
#pragma unroll
      for (int p = 0; p < 3; p++){
        float4 b4 = *(const float4*)(b_in + p*C_DIM + h*DH + c4);
        float bb[4] = {b4.x, b4.y, b4.z, b4.w};
        f16x4 s0v, s1v;
#pragma unroll
        for (int r = 0; r < 4; r++){
          s0v[r] = (_Float16)(acc[p][0][r] + bb[r]);
          s1v[r] = (_Float16)(acc[p][1][r] + bb[r]);
        }
        if (p < 2){
          *(f16x4*)(qk + l15*QKP      + p*64 + c4) = s0v;
          *(f16x4*)(qk + (16+l15)*QKP + p*64 + c4) = s1v;
        } else {
          *(f16x4*)(vv + l15*VVP      + c4) = s0v;
          *(f16x4*)(vv + (16+l15)*VVP + c4) = s1v;
        }
      }
    }
    __syncthreads();                        // q,k,v complete for this head
    // ---- attention for head h: wave wv handles l_loc = wv, lane = nn*8+mm ----
    {
      int nn = lane >> 3, mm = lane & 7;
      int tq = wv*8 + nn;
      const _Float16* qrow = qk + tq*QKP;              // broadcast over mm
      const _Float16* krow = qk + (wv*8 + mm)*QKP + 64;
      float s = 0.f;
#pragma unroll
      for (int d8 = 0; d8 < 8; d8++){
        F8u q8, k8;
        q8.v = *(const f16x8*)(qrow + d8*8);
        k8.v = *(const f16x8*)(krow + d8*8);
#if __has_builtin(__builtin_amdgcn_fdot2)
#pragma unroll
        for (int j2 = 0; j2 < 4; j2++)
          s = __builtin_amdgcn_fdot2(q8.p[j2], k8.p[j2], s, false);
#else
#pragma unroll
        for (int j = 0; j < 8; j++) s += (float)q8.v[j] * (float)k8.v[j];
#endif
      }
      s *= 0.125f;                          // 1/sqrt(64)
      float mx = s;
#pragma unroll
      for (int o = 1; o < 8; o <<= 1) mx = fmaxf(mx, __shfl_xor(mx, o));
      float e = __expf(s - mx);
      float sum = e;
#pragma unroll
      for (int o = 1; o < 8; o <<= 1) sum += __shfl_xor(sum, o);
      float attnw = e / sum;
      // ctx: this thread owns d-slice [mm*8, mm*8+8) of token tq
      float c8[8] = {0,0,0,0,0,0,0,0};
#pragma unroll
      for (int mp = 0; mp < 8; mp++){
        float aw = __shfl(attnw, (nn<<3) | mp);
        f16x8 v8 = *(const f16x8*)(vv + (wv*8 + mp)*VVP + mm*8);
#pragma unroll
        for (int j = 0; j < 8; j++) c8[j] += aw * (float)v8[j];
      }
      f16x8 cp;
#pragma unroll
      for (int j = 0; j < 8; j++) cp[j] = (_Float16)c8[j];
      if (h == 0)      cpk0 = cp;
      else if (h == 1) cpk1 = cp;
      else if (h == 2) cpk2 = cp;
      else {
        // A is dead (last GEMM read barrier-separated): write all 4 heads' ctx
        _Float16* crow = ctx + tq*256;
        *(f16x8*)(crow + ((( 0 + mm) ^ tq))*8) = cpk0;
        *(f16x8*)(crow + ((( 8 + mm) ^ tq))*8) = cpk1;
        *(f16x8*)(crow + (((16 + mm) ^ tq))*8) = cpk2;
        *(f16x8*)(crow + (((24 + mm) ^ tq))*8) = cp;
      }
    }
  }
  __syncthreads();  // ctx complete; qk/vv dead -> att may be written

  // ================= attended = ctx @ W_out^T + b_out (fp16 MFMA) =============
  {
    f16x8 wo[2][4];                         // ring lives entirely inside this phase
    OSET(wo[0], 0);
    OSET(wo[1], 1);
    f32x4 z = {0.f,0.f,0.f,0.f};
    f32x4 acc[4][2];
#pragma unroll
    for (int nt = 0; nt < 4; nt++){ acc[nt][0] = z; acc[nt][1] = z; }
#pragma unroll
    for (int kc = 0; kc < 8; kc++){
      int s0 = quad + 4*kc;
      int r1 = 16 + l15;
      f16x8 a0 = *(const f16x8*)(ctx + l15*256 + ((s0 ^ l15))*8);
      f16x8 a1 = *(const f16x8*)(ctx + r1*256  + ((s0 ^ r1))*8);
#pragma unroll
      for (int nt = 0; nt < 4; nt++){
        acc[nt][0] = __builtin_amdgcn_mfma_f32_16x16x32_f16(wo[kc&1][nt], a0, acc[nt][0], 0,0,0);
        acc[nt][1] = __builtin_amdgcn_mfma_f32_16x16x32_f16(wo[kc&1][nt], a1, acc[nt][1], 0,0,0);
      }
      if (kc < 6) OSET(wo[kc&1], kc+2);     // in-phase 2-ahead ring
    }
    // ctx (region1) and att (region2) are disjoint: no barrier needed here
#pragma unroll
    for (int nt = 0; nt < 4; nt++){
      int c4 = wv*64 + nt*16 + quad*4;
      float4 b4 = *(const float4*)(b_out + c4);
      float bb[4] = {b4.x, b4.y, b4.z, b4.w};
      f16x4 s0v, s1v;
#pragma unroll
      for (int r = 0; r < 4; r++){
        s0v[r] = (_Float16)(acc[nt][0][r] + bb[r]);
        s1v[r] = (_Float16)(acc[nt][1][r] + bb[r]);
      }
      int slot = c4 >> 3, jo = c4 & 7;
      *(f16x4*)(att + l15*256      + ((slot ^ l15))*8      + jo) = s0v;
      *(f16x4*)(att + (16+l15)*256 + ((slot ^ (16+l15)))*8 + jo) = s1v;
    }
  }
  __syncthreads();  // att ready; ctx dead -> g1s may be written

  // ================= gate hidden: g1 = relu(att @ Wg1^T + b) =================
  {
    f32x4 acc0 = {0.f,0.f,0.f,0.f}, acc1 = {0.f,0.f,0.f,0.f};
    f16x8 wg0 = *(const f16x8*)(wbg1);            // in-phase 2-deep ring
    f16x8 wg1f = *(const f16x8*)(wbg1 + 512);
#pragma unroll
    for (int kc = 0; kc < 8; kc++){
      int s0 = quad + 4*kc;
      int r1 = 16 + l15;
      f16x8 a0 = *(const f16x8*)(att + l15*256 + ((s0 ^ l15))*8);
      f16x8 a1 = *(const f16x8*)(att + r1*256  + ((s0 ^ r1))*8);
      f16x8 w = (kc & 1) ? wg1f : wg0;
      acc0 = __builtin_amdgcn_mfma_f32_16x16x32_f16(w, a0, acc0, 0,0,0);
      acc1 = __builtin_amdgcn_mfma_f32_16x16x32_f16(w, a1, acc1, 0,0,0);
      if (kc < 6){
        if (kc & 1) wg1f = *(const f16x8*)(wbg1 + (kc+2)*512);
        else        wg0  = *(const f16x8*)(wbg1 + (kc+2)*512);
      }
    }
    int c4 = wv*16 + quad*4;                // 4 consecutive hidden cols
    float4 b4 = *(const float4*)(b_g1 + c4);
    float bb[4] = {b4.x, b4.y, b4.z, b4.w};
    float4 o0, o1;
    o0.x = fmaxf(acc0[0]+bb[0], 0.f); o0.y = fmaxf(acc0[1]+bb[1], 0.f);
    o0.z = fmaxf(acc0[2]+bb[2], 0.f); o0.w = fmaxf(acc0[3]+bb[3], 0.f);
    o1.x = fmaxf(acc1[0]+bb[0], 0.f); o1.y = fmaxf(acc1[1]+bb[1], 0.f);
    o1.z = fmaxf(acc1[2]+bb[2], 0.f); o1.w = fmaxf(acc1[3]+bb[3], 0.f);
    *(float4*)(g1s + l15*GPAD      + c4) = o0;
    *(float4*)(g1s + (16+l15)*GPAD + c4) = o1;
  }
  __syncthreads();

  // ---- gate scalar + sigmoid (8 threads per token, 32 tokens) ----
  {
    int t = tid >> 3, part = tid & 7;
    const float* g1r = g1s + t*GPAD + part*8;
    const float* w2p = w2 + part*8;
    float s = 0.f;
#pragma unroll
    for (int j = 0; j < 8; j++) s += g1r[j] * w2p[j];
    s += __shfl_xor(s, 1);
    s += __shfl_xor(s, 2);
    s += __shfl_xor(s, 4);
    if (part == 0) gl[t] = 1.f / (1.f + __expf(-(s + b2[0])));
  }
  __syncthreads();
  // ---- softmax over views (4 l's) ----
  if (tid < 4){
    float v[8]; float mx = -1e30f;
    for (int n = 0; n < 8; n++){ v[n] = gl[tid*8+n]; mx = fmaxf(mx, v[n]); }
    float sum = 0.f;
    for (int n = 0; n < 8; n++){ v[n] = __expf(v[n]-mx); sum += v[n]; }
    float inv = 1.f/sum;
    for (int n = 0; n < 8; n++) wgt[tid*8+n] = v[n]*inv;
  }
  __syncthreads();

  // ---- fused = sum_n w_n * attended, then LayerNorm over C ----
  float f8[8];
  const int lfl = tid >> 5, ccf = tid & 31;   // lfl 0..3 valid (tid<128)
  if (tid < 128){
    float wloc[8];
#pragma unroll
    for (int n = 0; n < 8; n++) wloc[n] = wgt[lfl*8+n];
#pragma unroll
    for (int j = 0; j < 8; j++) f8[j] = 0.f;
#pragma unroll
    for (int n = 0; n < 8; n++){
      int row = lfl*8 + n;
      f16x8 a8 = *(const f16x8*)(att + row*256 + ((ccf ^ row))*8);
      float aw = wloc[n];
#pragma unroll
      for (int j = 0; j < 8; j++) f8[j] += aw * (float)a8[j];
    }
    float s = 0.f, s2 = 0.f;
#pragma unroll
    for (int j = 0; j < 8; j++){ s += f8[j]; s2 += f8[j]*f8[j]; }
    red1[lfl*32 + ccf] = s;
    red2[lfl*32 + ccf] = s2;
  }
  __syncthreads();
  if (tid < 4){
    float s = 0.f, s2 = 0.f;
    for (int i = 0; i < 32; i++){ s += red1[tid*32+i]; s2 += red2[tid*32+i]; }
    float mu = s * (1.f/256.f);
    float var = s2 * (1.f/256.f) - mu*mu;
    mus[tid] = mu;
    rvs[tid] = rsqrtf(var + 1e-5f);
  }
  __syncthreads();
  if (tid < 128){
    float mu = mus[lfl], rv = rvs[lfl];
    long lg = (long)blockIdx.x * TL + lfl;
    float* op = out + lg * C_DIM + ccf*8;
    float o8[8];
#pragma unroll
    for (int j = 0; j < 8; j++){
      int c = ccf*8 + j;
      o8[j] = (f8[j]-mu)*rv*ln_g[c] + ln_b[c];
    }
    *(float4*)(op)   = make_float4(o8[0],o8[1],o8[2],o8[3]);
    *(float4*)(op+4) = make_float4(o8[4],o8[5],o8[6],o8[7]);
  }
}

extern "C" void kernel_launch(void* const* d_in, const int* in_sizes, int n_in,
                              void* d_out, int out_size, void* d_ws, size_t ws_size,
                              hipStream_t stream){
  const float* feat  = (const float*)d_in[0];
  const float* vw    = (const float*)d_in[1];
  const float* vb    = (const float*)d_in[2];
  const float* w_in  = (const float*)d_in[3];
  const float* b_in  = (const float*)d_in[4];
  const float* w_out = (const float*)d_in[5];
  const float* b_out = (const float*)d_in[6];
  const float* w_g1  = (const float*)d_in[7];
  const float* b_g1  = (const float*)d_in[8];
  const float* w2    = (const float*)d_in[9];
  const float* b2    = (const float*)d_in[10];
  const float* lng   = (const float*)d_in[11];
  const float* lnb   = (const float*)d_in[12];

  char* ws = (char*)d_ws;
  float*    view_info = (float*)ws;               //   8192 B
  _Float16* win_pk  = (_Float16*)(ws + 8192);     // 393216 B (packed fp16)
  _Float16* wout_pk = (_Float16*)(ws + 401408);   // 131072 B
  _Float16* wg1_pk  = (_Float16*)(ws + 532480);   //  32768 B   total 565248 B

  prep_kernel<<<256, 256, 0, stream>>>(vw, vb, w_in, w_out, w_g1,
                                       view_info, win_pk, wout_pk, wg1_pk);
  fused_kernel<<<L_DIM/TL, NTHREADS, 32768, stream>>>(
      feat, view_info, win_pk, wout_pk, wg1_pk,
      b_in, b_out, b_g1, w2, b2, lng, lnb, (float*)d_out);
}